// Round 2
// baseline (552.264 us; speedup 1.0000x reference)
//
#include <hip/hip_runtime.h>
#include <hip/hip_bf16.h>
#include <math.h>

typedef unsigned short u16;

#define NB 8
#define NN 56          // h == w
#define M2 112         // 2n
#define EMB 192
#define D1 576
#define TOK (NB*NN*NN) // 25088

__device__ __forceinline__ float bf2f(unsigned int u) {
    union { unsigned int i; float f; } v; v.i = u << 16; return v.f;
}
__device__ __forceinline__ u16 f2bf(float f) {
    union { float f; unsigned int i; } v; v.f = f;
    unsigned int x = v.i;
    return (u16)((x + 0x7fffu + ((x >> 16) & 1u)) >> 16);
}
__device__ __forceinline__ ushort4 pack4(float a, float b, float c, float d) {
    ushort4 r; r.x = f2bf(a); r.y = f2bf(b); r.z = f2bf(c); r.w = f2bf(d); return r;
}
__device__ __forceinline__ void ld8f(const float* p, float* f) {
    float4 a = *(const float4*)p;
    float4 b = *(const float4*)(p + 4);
    f[0] = a.x; f[1] = a.y; f[2] = a.z; f[3] = a.w;
    f[4] = b.x; f[5] = b.y; f[6] = b.z; f[7] = b.w;
}
__device__ __forceinline__ float silu(float x) {
    return x / (1.0f + __expf(-x));
}

// ---------------- K1: RPE MLP + decay -> A1, A2 (fp32, 112 x 576 each) ----
__global__ __launch_bounds__(576) void rpe_kernel(
    const float* __restrict__ slope,
    const float* w0a, const float* b0a, const float* wsa, const float* bsa,
    const float* woa, const float* boa,
    const float* w0b, const float* b0b, const float* wsb, const float* bsb,
    const float* wob, const float* bob,
    float* __restrict__ A1, float* __restrict__ A2)
{
    int wq  = blockIdx.x / M2;
    int row = blockIdx.x % M2;
    const float* w0 = wq ? w0b : w0a;  const float* b0 = wq ? b0b : b0a;
    const float* ws = wq ? wsb : wsa;  const float* bs = wq ? bsb : bsa;
    const float* wo = wq ? wob : woa;  const float* bo = wq ? bob : boa;
    float* A = wq ? A2 : A1;

    // rpe input value for this row: [0, 1..55, 0, -1..-55]
    float tval = (row == 0 || row == 56) ? 0.0f
               : (row < 56 ? (float)row : -(float)(row - 56));
    int kexp = (row == 0 || row == 56) ? 0 : (row < 56 ? row : 112 - row);

    __shared__ float h[32], g[32];
    int t = threadIdx.x;
    if (t < 32) h[t] = tval * w0[t] + b0[t];
    __syncthreads();
    for (int L = 0; L < 3; L++) {
        if (t < 32) g[t] = fmaxf(h[t], 0.0f);
        __syncthreads();
        float hn = 0.0f;
        if (t < 32) {
            hn = bs[L * 32 + t];
            for (int k = 0; k < 32; k++)
                hn = fmaf(g[k], ws[(L * 32 + t) * 32 + k], hn);
        }
        __syncthreads();
        if (t < 32) h[t] = hn;
        __syncthreads();
    }
    if (t < 32) g[t] = fmaxf(h[t], 0.0f);
    __syncthreads();

    float o = bo[t];
    for (int k = 0; k < 32; k++)
        o = fmaf(g[k], wo[t * 32 + k], o);

    float sl = slope[t];
    sl = 0.95f + 0.05f * fminf(fmaxf(sl, 0.0f), 1.0f);
    float dec = powf(sl, (float)kexp);
    A[row * D1 + t] = o * dec;
}

// ---------------- K2: P = silu(XPw+b), QV = silu(XQw+b)*silu(XVw+b) -------
// X: TOK x 192 f32. Tile 64x64, K=192, 256 threads, 4x4 micro-tile x3 acc.
__global__ __launch_bounds__(256) void proj_kernel(
    const float* __restrict__ x,
    const float* __restrict__ pw, const float* __restrict__ pb,
    const float* __restrict__ qw, const float* __restrict__ qb,
    const float* __restrict__ vw, const float* __restrict__ vb,
    u16* __restrict__ P, u16* __restrict__ QV)
{
    __shared__ float xs[32][68];
    __shared__ float wsh[3][32][68];
    int m0 = blockIdx.x * 64, n0 = blockIdx.y * 64;
    int t = threadIdx.x;
    int r = t >> 2, cg = t & 3;        // staging: row 0..63, col-group 0..3
    int tx = t & 15, ty = t >> 4;      // compute: n-group, m-group
    float accp[4][4] = {}, accq[4][4] = {}, accv[4][4] = {};
    const float* wptr[3] = { pw, qw, vw };

    for (int k0 = 0; k0 < EMB; k0 += 32) {
        float f[8];
        ld8f(x + (m0 + r) * EMB + k0 + cg * 8, f);
        #pragma unroll
        for (int j = 0; j < 8; j++) xs[cg * 8 + j][r] = f[j];
        #pragma unroll
        for (int wi = 0; wi < 3; wi++) {
            ld8f(wptr[wi] + (n0 + r) * EMB + k0 + cg * 8, f);
            #pragma unroll
            for (int j = 0; j < 8; j++) wsh[wi][cg * 8 + j][r] = f[j];
        }
        __syncthreads();
        #pragma unroll 4
        for (int kk = 0; kk < 32; kk++) {
            float4 xa = *(const float4*)&xs[kk][ty * 4];
            float ax[4] = { xa.x, xa.y, xa.z, xa.w };
            float4 b0v = *(const float4*)&wsh[0][kk][tx * 4];
            float4 b1v = *(const float4*)&wsh[1][kk][tx * 4];
            float4 b2v = *(const float4*)&wsh[2][kk][tx * 4];
            float bp[4] = { b0v.x, b0v.y, b0v.z, b0v.w };
            float bq[4] = { b1v.x, b1v.y, b1v.z, b1v.w };
            float bv[4] = { b2v.x, b2v.y, b2v.z, b2v.w };
            #pragma unroll
            for (int i = 0; i < 4; i++)
                #pragma unroll
                for (int j = 0; j < 4; j++) {
                    accp[i][j] = fmaf(ax[i], bp[j], accp[i][j]);
                    accq[i][j] = fmaf(ax[i], bq[j], accq[i][j]);
                    accv[i][j] = fmaf(ax[i], bv[j], accv[i][j]);
                }
        }
        __syncthreads();
    }
    // epilogue
    #pragma unroll
    for (int i = 0; i < 4; i++) {
        int m = m0 + ty * 4 + i;
        int n = n0 + tx * 4;
        float pr[4], qvr[4];
        #pragma unroll
        for (int j = 0; j < 4; j++) {
            float pv  = silu(accp[i][j] + pb[n + j]);
            float qv_ = silu(accq[i][j] + qb[n + j]);
            float vv_ = silu(accv[i][j] + vb[n + j]);
            pr[j] = pv; qvr[j] = qv_ * vv_;
        }
        *(ushort4*)&P[m * D1 + n]  = pack4(pr[0], pr[1], pr[2], pr[3]);
        *(ushort4*)&QV[m * D1 + n] = pack4(qvr[0], qvr[1], qvr[2], qvr[3]);
    }
}

// ---------------- K3: Toeplitz along W -> O (fp32) ------------------------
__global__ __launch_bounds__(256) void tno_w_kernel(
    const u16* __restrict__ QV, const float* __restrict__ A1,
    float* __restrict__ O)
{
    int bh = blockIdx.x;            // 0..447  (b*56 + h)
    int d0 = blockIdx.y * 64;
    __shared__ float qs[56][64];
    __shared__ float as[111][64];   // as[55 + lag][d]
    int t = threadIdx.x;
    for (int idx = t; idx < 56 * 64; idx += 256) {
        int w = idx >> 6, d = idx & 63;
        qs[w][d] = bf2f(QV[(bh * 56 + w) * D1 + d0 + d]);
    }
    for (int idx = t; idx < 111 * 64; idx += 256) {
        int p = idx >> 6, d = idx & 63;
        int l = p - 55;
        int rowi = (l >= 0) ? l : l + 112;
        as[p][d] = A1[rowi * D1 + d0 + d];
    }
    __syncthreads();
    int d = t & 63, ig = t >> 6;
    int i0 = ig * 14;
    float acc[14] = {};
    for (int j = 0; j < 56; j++) {
        float q = qs[j][d];
        const float* ap = &as[i0 + 55 - j][d];
        #pragma unroll
        for (int ii = 0; ii < 14; ii++)
            acc[ii] = fmaf(ap[ii * 64], q, acc[ii]);
    }
    #pragma unroll
    for (int ii = 0; ii < 14; ii++)
        O[(bh * 56 + i0 + ii) * D1 + d0 + d] = acc[ii];
}

// ---------------- K4: Toeplitz along H, O += ------------------------------
__global__ __launch_bounds__(256) void tno_h_kernel(
    const u16* __restrict__ QV, const float* __restrict__ A2,
    float* __restrict__ O)
{
    int bw = blockIdx.x;            // b*56 + w
    int b = bw / 56, wc = bw % 56;
    int d0 = blockIdx.y * 64;
    __shared__ float qs[56][64];
    __shared__ float as[111][64];
    int t = threadIdx.x;
    for (int idx = t; idx < 56 * 64; idx += 256) {
        int h = idx >> 6, d = idx & 63;
        qs[h][d] = bf2f(QV[((b * 56 + h) * 56 + wc) * D1 + d0 + d]);
    }
    for (int idx = t; idx < 111 * 64; idx += 256) {
        int p = idx >> 6, d = idx & 63;
        int l = p - 55;
        int rowi = (l >= 0) ? l : l + 112;
        as[p][d] = A2[rowi * D1 + d0 + d];
    }
    __syncthreads();
    int d = t & 63, ig = t >> 6;
    int i0 = ig * 14;
    float acc[14] = {};
    for (int j = 0; j < 56; j++) {
        float q = qs[j][d];
        const float* ap = &as[i0 + 55 - j][d];
        #pragma unroll
        for (int ii = 0; ii < 14; ii++)
            acc[ii] = fmaf(ap[ii * 64], q, acc[ii]);
    }
    #pragma unroll
    for (int ii = 0; ii < 14; ii++) {
        float* op = &O[((b * 56 + (i0 + ii)) * 56 + wc) * D1 + d0 + d];
        *op += acc[ii];
    }
}

// ---------------- K5: out = (P .* O) @ o_w^T + o_b ------------------------
// M=25088, N=192, K=576. Tile 64x64.
__global__ __launch_bounds__(256) void outproj_kernel(
    const u16* __restrict__ P, const float* __restrict__ O,
    const float* __restrict__ ow, const float* __restrict__ ob,
    float* __restrict__ out)
{
    __shared__ float us[32][68];
    __shared__ float wsh[32][68];
    int m0 = blockIdx.x * 64, n0 = blockIdx.y * 64;
    int t = threadIdx.x;
    int r = t >> 2, cg = t & 3;
    int tx = t & 15, ty = t >> 4;
    float acc[4][4] = {};
    for (int k0 = 0; k0 < D1; k0 += 32) {
        const u16* pp = P + (m0 + r) * D1 + k0 + cg * 8;
        uint4 pu = *(const uint4*)pp;
        float pf[8] = { bf2f(pu.x & 0xffffu), bf2f(pu.x >> 16),
                        bf2f(pu.y & 0xffffu), bf2f(pu.y >> 16),
                        bf2f(pu.z & 0xffffu), bf2f(pu.z >> 16),
                        bf2f(pu.w & 0xffffu), bf2f(pu.w >> 16) };
        const float* op = O + (m0 + r) * D1 + k0 + cg * 8;
        float4 o1 = *(const float4*)op;
        float4 o2 = *(const float4*)(op + 4);
        float ov[8] = { o1.x, o1.y, o1.z, o1.w, o2.x, o2.y, o2.z, o2.w };
        #pragma unroll
        for (int j = 0; j < 8; j++) us[cg * 8 + j][r] = pf[j] * ov[j];
        float wf[8];
        ld8f(ow + (n0 + r) * D1 + k0 + cg * 8, wf);
        #pragma unroll
        for (int j = 0; j < 8; j++) wsh[cg * 8 + j][r] = wf[j];
        __syncthreads();
        #pragma unroll 4
        for (int kk = 0; kk < 32; kk++) {
            float4 ua = *(const float4*)&us[kk][ty * 4];
            float au[4] = { ua.x, ua.y, ua.z, ua.w };
            float4 wb = *(const float4*)&wsh[kk][tx * 4];
            float bw[4] = { wb.x, wb.y, wb.z, wb.w };
            #pragma unroll
            for (int i = 0; i < 4; i++)
                #pragma unroll
                for (int j = 0; j < 4; j++)
                    acc[i][j] = fmaf(au[i], bw[j], acc[i][j]);
        }
        __syncthreads();
    }
    #pragma unroll
    for (int i = 0; i < 4; i++) {
        int m = m0 + ty * 4 + i;
        int n = n0 + tx * 4;
        float4 r4;
        r4.x = acc[i][0] + ob[n + 0];
        r4.y = acc[i][1] + ob[n + 1];
        r4.z = acc[i][2] + ob[n + 2];
        r4.w = acc[i][3] + ob[n + 3];
        *(float4*)&out[m * EMB + n] = r4;
    }
}

extern "C" void kernel_launch(void* const* d_in, const int* in_sizes, int n_in,
                              void* d_out, int out_size, void* d_ws, size_t ws_size,
                              hipStream_t stream)
{
    (void)in_sizes; (void)n_in; (void)out_size; (void)ws_size;
    const float* x     = (const float*)d_in[0];
    const float* p_w   = (const float*)d_in[1];
    const float* p_b   = (const float*)d_in[2];
    const float* q_w   = (const float*)d_in[3];
    const float* q_b   = (const float*)d_in[4];
    const float* v_w   = (const float*)d_in[5];
    const float* v_b   = (const float*)d_in[6];
    const float* o_w   = (const float*)d_in[7];
    const float* o_b   = (const float*)d_in[8];
    const float* slope = (const float*)d_in[9];
    const float* t1_w0 = (const float*)d_in[10];
    const float* t1_b0 = (const float*)d_in[11];
    const float* t1_ws = (const float*)d_in[12];
    const float* t1_bs = (const float*)d_in[13];
    const float* t1_wo = (const float*)d_in[14];
    const float* t1_bo = (const float*)d_in[15];
    const float* t2_w0 = (const float*)d_in[16];
    const float* t2_b0 = (const float*)d_in[17];
    const float* t2_ws = (const float*)d_in[18];
    const float* t2_bs = (const float*)d_in[19];
    const float* t2_wo = (const float*)d_in[20];
    const float* t2_bo = (const float*)d_in[21];

    char* ws = (char*)d_ws;
    float* A1 = (float*)ws;                                // 112*576*4 = 258048
    float* A2 = (float*)(ws + 258048);
    u16*   P  = (u16*)(ws + 516096);                       // TOK*D1*2 = 28901376
    u16*   QV = (u16*)(ws + 516096 + 28901376);
    float* O  = (float*)(ws + 516096 + 2u * 28901376u);    // TOK*D1*4

    rpe_kernel<<<224, 576, 0, stream>>>(slope,
        t1_w0, t1_b0, t1_ws, t1_bs, t1_wo, t1_bo,
        t2_w0, t2_b0, t2_ws, t2_bs, t2_wo, t2_bo, A1, A2);
    proj_kernel<<<dim3(TOK / 64, D1 / 64), 256, 0, stream>>>(
        x, p_w, p_b, q_w, q_b, v_w, v_b, P, QV);
    tno_w_kernel<<<dim3(NB * NN, D1 / 64), 256, 0, stream>>>(QV, A1, O);
    tno_h_kernel<<<dim3(NB * NN, D1 / 64), 256, 0, stream>>>(QV, A2, O);
    outproj_kernel<<<dim3(TOK / 64, EMB / 64), 256, 0, stream>>>(
        P, O, o_w, o_b, (float*)d_out);
}

// Round 3
// 307.509 us; speedup vs baseline: 1.7959x; 1.7959x over previous
//
#include <hip/hip_runtime.h>
#include <hip/hip_bf16.h>
#include <math.h>

typedef unsigned short u16;
typedef short bf16x8 __attribute__((ext_vector_type(8)));
typedef float f32x4 __attribute__((ext_vector_type(4)));

#define NB 8
#define NN 56          // h == w
#define M2 112         // 2n
#define EMB 192
#define D1 576
#define TOK (NB*NN*NN) // 25088

__device__ __forceinline__ float bf2f(unsigned int u) {
    union { unsigned int i; float f; } v; v.i = u << 16; return v.f;
}
__device__ __forceinline__ u16 f2bf(float f) {
    union { float f; unsigned int i; } v; v.f = f;
    unsigned int x = v.i;
    return (u16)((x + 0x7fffu + ((x >> 16) & 1u)) >> 16);
}
__device__ __forceinline__ float silu(float x) {
    return x / (1.0f + __expf(-x));
}
__device__ __forceinline__ void async16(void* lds, const void* g) {
    __builtin_amdgcn_global_load_lds(
        (const __attribute__((address_space(1))) void*)g,
        (__attribute__((address_space(3))) void*)lds, 16, 0, 0);
}

// ---------------- K0: fp32 -> bf16 convert (x, pw, qw, vw, ow) ------------
#define XCH (TOK*EMB/4)          // 1204224 float4 chunks for x
#define WCH (D1*EMB/4)           // 27648 per weight matrix
__global__ __launch_bounds__(256) void convert_kernel(
    const float* __restrict__ x,
    const float* __restrict__ pw, const float* __restrict__ qw,
    const float* __restrict__ vw, const float* __restrict__ ow,
    u16* __restrict__ xb, u16* __restrict__ wb, u16* __restrict__ owb)
{
    int tid = blockIdx.x * 256 + threadIdx.x;
    const float* src; u16* dst; int off;
    if (tid < XCH) { src = x; dst = xb; off = tid; }
    else {
        int r = tid - XCH;
        int seg = r / WCH; off = r % WCH;
        if (seg == 0)      { src = pw; dst = wb; }
        else if (seg == 1) { src = qw; dst = wb + D1*EMB; }
        else if (seg == 2) { src = vw; dst = wb + 2*D1*EMB; }
        else if (seg == 3) { src = ow; dst = owb; }
        else return;
    }
    float4 f = *(const float4*)(src + off * 4);
    ushort4 o;
    o.x = f2bf(f.x); o.y = f2bf(f.y); o.z = f2bf(f.z); o.w = f2bf(f.w);
    *(ushort4*)(dst + off * 4) = o;
}

// ---------------- K1: RPE MLP + decay -> A1, A2 (fp32, 112 x 576 each) ----
__global__ __launch_bounds__(576) void rpe_kernel(
    const float* __restrict__ slope,
    const float* w0a, const float* b0a, const float* wsa, const float* bsa,
    const float* woa, const float* boa,
    const float* w0b, const float* b0b, const float* wsb, const float* bsb,
    const float* wob, const float* bob,
    float* __restrict__ A1, float* __restrict__ A2)
{
    int wq  = blockIdx.x / M2;
    int row = blockIdx.x % M2;
    const float* w0 = wq ? w0b : w0a;  const float* b0 = wq ? b0b : b0a;
    const float* ws = wq ? wsb : wsa;  const float* bs = wq ? bsb : bsa;
    const float* wo = wq ? wob : woa;  const float* bo = wq ? bob : boa;
    float* A = wq ? A2 : A1;

    float tval = (row == 0 || row == 56) ? 0.0f
               : (row < 56 ? (float)row : -(float)(row - 56));
    int kexp = (row == 0 || row == 56) ? 0 : (row < 56 ? row : 112 - row);

    __shared__ float h[32], g[32];
    int t = threadIdx.x;
    if (t < 32) h[t] = tval * w0[t] + b0[t];
    __syncthreads();
    for (int L = 0; L < 3; L++) {
        if (t < 32) g[t] = fmaxf(h[t], 0.0f);
        __syncthreads();
        float hn = 0.0f;
        if (t < 32) {
            hn = bs[L * 32 + t];
            for (int k = 0; k < 32; k++)
                hn = fmaf(g[k], ws[(L * 32 + t) * 32 + k], hn);
        }
        __syncthreads();
        if (t < 32) h[t] = hn;
        __syncthreads();
    }
    if (t < 32) g[t] = fmaxf(h[t], 0.0f);
    __syncthreads();

    float o = bo[t];
    for (int k = 0; k < 32; k++)
        o = fmaf(g[k], wo[t * 32 + k], o);

    float sl = slope[t];
    sl = 0.95f + 0.05f * fminf(fmaxf(sl, 0.0f), 1.0f);
    float dec = powf(sl, (float)kexp);
    A[row * D1 + t] = o * dec;
}

// ---------------- K2: MFMA proj: P = silu(XW_p), QV = silu(XW_q)*silu(XW_v)
// M=TOK, N=576, K=192. Tile 128x64, BK=32, 4 waves (2x2), wave tile 64x32.
__global__ __launch_bounds__(256) void proj_kernel(
    const u16* __restrict__ xb, const u16* __restrict__ wb,
    const float* __restrict__ pb, const float* __restrict__ qb,
    const float* __restrict__ vb,
    u16* __restrict__ P, u16* __restrict__ QV)
{
    __shared__ u16 As[128 * 32];     // 8 KB  [row][k] row-major
    __shared__ u16 Bs[3 * 64 * 32];  // 12 KB [mat][n][k]
    int m0 = blockIdx.x * 128, n0 = blockIdx.y * 64;
    int t = threadIdx.x;
    int l = t & 63, wave = t >> 6;
    int wm = wave >> 1, wn = wave & 1;
    int col16 = l & 15, q = l >> 4;

    f32x4 accp[4][2], accq[4][2], accv[4][2];
    #pragma unroll
    for (int i = 0; i < 4; i++)
        #pragma unroll
        for (int j = 0; j < 2; j++) {
            accp[i][j] = (f32x4){0,0,0,0};
            accq[i][j] = (f32x4){0,0,0,0};
            accv[i][j] = (f32x4){0,0,0,0};
        }

    for (int k0 = 0; k0 < EMB; k0 += 32) {
        // stage A: 512 16B chunks
        #pragma unroll
        for (int i = 0; i < 2; i++) {
            int c = t + i * 256;
            int r = c >> 2, cg = c & 3;
            async16(&As[c * 8], xb + (m0 + r) * EMB + k0 + cg * 8);
        }
        // stage B: 768 16B chunks (3 matrices x 64 x 32)
        #pragma unroll
        for (int i = 0; i < 3; i++) {
            int c = t + i * 256;
            int mat = c >> 8, cc = c & 255;
            int r = cc >> 2, cg = cc & 3;
            async16(&Bs[c * 8], wb + mat * (D1 * EMB) + (n0 + r) * EMB + k0 + cg * 8);
        }
        __syncthreads();

        bf16x8 af[4];
        #pragma unroll
        for (int mt = 0; mt < 4; mt++)
            af[mt] = *(const bf16x8*)&As[(wm * 64 + mt * 16 + col16) * 32 + q * 8];
        bf16x8 bfr[3][2];
        #pragma unroll
        for (int mat = 0; mat < 3; mat++)
            #pragma unroll
            for (int nt = 0; nt < 2; nt++)
                bfr[mat][nt] = *(const bf16x8*)&Bs[mat * 2048 +
                    (wn * 32 + nt * 16 + col16) * 32 + q * 8];
        #pragma unroll
        for (int mt = 0; mt < 4; mt++)
            #pragma unroll
            for (int nt = 0; nt < 2; nt++) {
                accp[mt][nt] = __builtin_amdgcn_mfma_f32_16x16x32_bf16(
                    af[mt], bfr[0][nt], accp[mt][nt], 0, 0, 0);
                accq[mt][nt] = __builtin_amdgcn_mfma_f32_16x16x32_bf16(
                    af[mt], bfr[1][nt], accq[mt][nt], 0, 0, 0);
                accv[mt][nt] = __builtin_amdgcn_mfma_f32_16x16x32_bf16(
                    af[mt], bfr[2][nt], accv[mt][nt], 0, 0, 0);
            }
        __syncthreads();
    }

    // epilogue: C layout col=lane&15, row=(lane>>4)*4+reg
    #pragma unroll
    for (int nt = 0; nt < 2; nt++) {
        int n = n0 + wn * 32 + nt * 16 + col16;
        float pbv = pb[n], qbv = qb[n], vbv = vb[n];
        #pragma unroll
        for (int mt = 0; mt < 4; mt++)
            #pragma unroll
            for (int r = 0; r < 4; r++) {
                int m = m0 + wm * 64 + mt * 16 + q * 4 + r;
                int idx = m * D1 + n;
                float pv  = silu(accp[mt][nt][r] + pbv);
                float qv_ = silu(accq[mt][nt][r] + qbv);
                float vv_ = silu(accv[mt][nt][r] + vbv);
                P[idx]  = f2bf(pv);
                QV[idx] = f2bf(qv_ * vv_);
            }
    }
}

// ---------------- K3: Toeplitz along W -> O (bf16) ------------------------
__global__ __launch_bounds__(256) void tno_w_kernel(
    const u16* __restrict__ QV, const float* __restrict__ A1,
    u16* __restrict__ O)
{
    int bh = blockIdx.x;            // b*56 + h
    int d0 = blockIdx.y * 64;
    __shared__ float qs[56][64];
    __shared__ float as[111][64];   // as[55 + lag][d]
    int t = threadIdx.x;
    for (int idx = t; idx < 56 * 64; idx += 256) {
        int w = idx >> 6, d = idx & 63;
        qs[w][d] = bf2f(QV[(bh * 56 + w) * D1 + d0 + d]);
    }
    for (int idx = t; idx < 111 * 64; idx += 256) {
        int p = idx >> 6, d = idx & 63;
        int lg = p - 55;
        int rowi = (lg >= 0) ? lg : lg + 112;
        as[p][d] = A1[rowi * D1 + d0 + d];
    }
    __syncthreads();
    int d = t & 63, ig = t >> 6;
    int i0 = ig * 14;
    float acc[14] = {};
    for (int j = 0; j < 56; j++) {
        float qv = qs[j][d];
        const float* ap = &as[i0 + 55 - j][d];
        #pragma unroll
        for (int ii = 0; ii < 14; ii++)
            acc[ii] = fmaf(ap[ii * 64], qv, acc[ii]);
    }
    #pragma unroll
    for (int ii = 0; ii < 14; ii++)
        O[(bh * 56 + i0 + ii) * D1 + d0 + d] = f2bf(acc[ii]);
}

// ---------------- K4: Toeplitz along H, fuse U = P .* (O + o2) ------------
// Writes U (bf16) in place over P (exact same index read-then-write).
__global__ __launch_bounds__(256) void tno_h_kernel(
    const u16* __restrict__ QV, const float* __restrict__ A2,
    const u16* __restrict__ O, u16* __restrict__ PU)
{
    int bw = blockIdx.x;            // b*56 + w
    int b = bw / 56, wc = bw % 56;
    int d0 = blockIdx.y * 64;
    __shared__ float qs[56][64];
    __shared__ float as[111][64];
    int t = threadIdx.x;
    for (int idx = t; idx < 56 * 64; idx += 256) {
        int h = idx >> 6, d = idx & 63;
        qs[h][d] = bf2f(QV[((b * 56 + h) * 56 + wc) * D1 + d0 + d]);
    }
    for (int idx = t; idx < 111 * 64; idx += 256) {
        int p = idx >> 6, d = idx & 63;
        int lg = p - 55;
        int rowi = (lg >= 0) ? lg : lg + 112;
        as[p][d] = A2[rowi * D1 + d0 + d];
    }
    __syncthreads();
    int d = t & 63, ig = t >> 6;
    int i0 = ig * 14;
    float acc[14] = {};
    for (int j = 0; j < 56; j++) {
        float qv = qs[j][d];
        const float* ap = &as[i0 + 55 - j][d];
        #pragma unroll
        for (int ii = 0; ii < 14; ii++)
            acc[ii] = fmaf(ap[ii * 64], qv, acc[ii]);
    }
    #pragma unroll
    for (int ii = 0; ii < 14; ii++) {
        int idx = ((b * 56 + (i0 + ii)) * 56 + wc) * D1 + d0 + d;
        float o = bf2f(O[idx]) + acc[ii];
        float p = bf2f(PU[idx]);
        PU[idx] = f2bf(p * o);
    }
}

// ---------------- K5: MFMA outproj: out = U @ ow^T + ob -------------------
// M=TOK, N=192, K=576. Tile 128x64, BK=32, 4 waves (2x2), wave tile 64x32.
__global__ __launch_bounds__(256) void outproj_kernel(
    const u16* __restrict__ U, const u16* __restrict__ owb,
    const float* __restrict__ ob, float* __restrict__ out)
{
    __shared__ u16 As[128 * 32];   // 8 KB
    __shared__ u16 Bs[64 * 32];    // 4 KB
    int m0 = blockIdx.x * 128, n0 = blockIdx.y * 64;
    int t = threadIdx.x;
    int l = t & 63, wave = t >> 6;
    int wm = wave >> 1, wn = wave & 1;
    int col16 = l & 15, q = l >> 4;

    f32x4 acc[4][2];
    #pragma unroll
    for (int i = 0; i < 4; i++)
        #pragma unroll
        for (int j = 0; j < 2; j++) acc[i][j] = (f32x4){0,0,0,0};

    for (int k0 = 0; k0 < D1; k0 += 32) {
        #pragma unroll
        for (int i = 0; i < 2; i++) {
            int c = t + i * 256;
            int r = c >> 2, cg = c & 3;
            async16(&As[c * 8], U + (m0 + r) * D1 + k0 + cg * 8);
        }
        {
            int c = t;                     // 256 chunks exactly
            int r = c >> 2, cg = c & 3;
            async16(&Bs[c * 8], owb + (n0 + r) * D1 + k0 + cg * 8);
        }
        __syncthreads();

        bf16x8 af[4];
        #pragma unroll
        for (int mt = 0; mt < 4; mt++)
            af[mt] = *(const bf16x8*)&As[(wm * 64 + mt * 16 + col16) * 32 + q * 8];
        bf16x8 bfr[2];
        #pragma unroll
        for (int nt = 0; nt < 2; nt++)
            bfr[nt] = *(const bf16x8*)&Bs[(wn * 32 + nt * 16 + col16) * 32 + q * 8];
        #pragma unroll
        for (int mt = 0; mt < 4; mt++)
            #pragma unroll
            for (int nt = 0; nt < 2; nt++)
                acc[mt][nt] = __builtin_amdgcn_mfma_f32_16x16x32_bf16(
                    af[mt], bfr[nt], acc[mt][nt], 0, 0, 0);
        __syncthreads();
    }

    #pragma unroll
    for (int nt = 0; nt < 2; nt++) {
        int n = n0 + wn * 32 + nt * 16 + col16;
        float obv = ob[n];
        #pragma unroll
        for (int mt = 0; mt < 4; mt++)
            #pragma unroll
            for (int r = 0; r < 4; r++) {
                int m = m0 + wm * 64 + mt * 16 + q * 4 + r;
                out[m * EMB + n] = acc[mt][nt][r] + obv;
            }
    }
}

extern "C" void kernel_launch(void* const* d_in, const int* in_sizes, int n_in,
                              void* d_out, int out_size, void* d_ws, size_t ws_size,
                              hipStream_t stream)
{
    (void)in_sizes; (void)n_in; (void)out_size; (void)ws_size;
    const float* x     = (const float*)d_in[0];
    const float* p_w   = (const float*)d_in[1];
    const float* p_b   = (const float*)d_in[2];
    const float* q_w   = (const float*)d_in[3];
    const float* q_b   = (const float*)d_in[4];
    const float* v_w   = (const float*)d_in[5];
    const float* v_b   = (const float*)d_in[6];
    const float* o_w   = (const float*)d_in[7];
    const float* o_b   = (const float*)d_in[8];
    const float* slope = (const float*)d_in[9];
    const float* t1_w0 = (const float*)d_in[10];
    const float* t1_b0 = (const float*)d_in[11];
    const float* t1_ws = (const float*)d_in[12];
    const float* t1_bs = (const float*)d_in[13];
    const float* t1_wo = (const float*)d_in[14];
    const float* t1_bo = (const float*)d_in[15];
    const float* t2_w0 = (const float*)d_in[16];
    const float* t2_b0 = (const float*)d_in[17];
    const float* t2_ws = (const float*)d_in[18];
    const float* t2_bs = (const float*)d_in[19];
    const float* t2_wo = (const float*)d_in[20];
    const float* t2_bo = (const float*)d_in[21];

    char* ws = (char*)d_ws;
    float* A1 = (float*)ws;                      // 258048 B
    float* A2 = (float*)(ws + 258048);           // 258048 B
    u16*   PU = (u16*)(ws + 516096);             // 28901376 B (P, later U)
    u16*   QV = (u16*)(ws + 29417472);           // 28901376 B
    u16*   O  = (u16*)(ws + 58318848);           // 28901376 B (bf16)
    u16*   xb = (u16*)(ws + 87220224);           // 9633792 B
    u16*   wb = (u16*)(ws + 96854016);           // 663552 B (pw,qw,vw bf16)
    u16*   owb= (u16*)(ws + 97517568);           // 221184 B

    convert_kernel<<<(XCH + 4*WCH + 255) / 256, 256, 0, stream>>>(
        x, p_w, q_w, v_w, o_w, xb, wb, owb);
    rpe_kernel<<<224, 576, 0, stream>>>(slope,
        t1_w0, t1_b0, t1_ws, t1_bs, t1_wo, t1_bo,
        t2_w0, t2_b0, t2_ws, t2_bs, t2_wo, t2_bo, A1, A2);
    proj_kernel<<<dim3(TOK / 128, D1 / 64), 256, 0, stream>>>(
        xb, wb, p_b, q_b, v_b, PU, QV);
    tno_w_kernel<<<dim3(NB * NN, D1 / 64), 256, 0, stream>>>(QV, A1, O);
    tno_h_kernel<<<dim3(NB * NN, D1 / 64), 256, 0, stream>>>(QV, A2, O, PU);
    outproj_kernel<<<dim3(TOK / 128, EMB / 64), 256, 0, stream>>>(
        PU, owb, o_b, (float*)d_out);
}

// Round 4
// 278.842 us; speedup vs baseline: 1.9806x; 1.1028x over previous
//
#include <hip/hip_runtime.h>
#include <hip/hip_bf16.h>
#include <math.h>

typedef unsigned short u16;
typedef short bf16x8 __attribute__((ext_vector_type(8)));
typedef float f32x4 __attribute__((ext_vector_type(4)));

#define NB 8
#define NN 56          // h == w
#define M2 112         // 2n
#define EMB 192
#define D1 576
#define TOK (NB*NN*NN) // 25088

__device__ __forceinline__ float bf2f(unsigned int u) {
    union { unsigned int i; float f; } v; v.i = u << 16; return v.f;
}
__device__ __forceinline__ u16 f2bf(float f) {
    union { float f; unsigned int i; } v; v.f = f;
    unsigned int x = v.i;
    return (u16)((x + 0x7fffu + ((x >> 16) & 1u)) >> 16);
}
__device__ __forceinline__ float silu(float x) {
    return x / (1.0f + __expf(-x));
}
__device__ __forceinline__ void async16(void* lds, const void* g) {
    __builtin_amdgcn_global_load_lds(
        (const __attribute__((address_space(1))) void*)g,
        (__attribute__((address_space(3))) void*)lds, 16, 0, 0);
}

// ---------------- K0: fp32 -> bf16 convert (x, pw, qw, vw, ow) ------------
#define XCH (TOK*EMB/4)
#define WCH (D1*EMB/4)
__global__ __launch_bounds__(256) void convert_kernel(
    const float* __restrict__ x,
    const float* __restrict__ pw, const float* __restrict__ qw,
    const float* __restrict__ vw, const float* __restrict__ ow,
    u16* __restrict__ xb, u16* __restrict__ wb, u16* __restrict__ owb)
{
    int tid = blockIdx.x * 256 + threadIdx.x;
    const float* src; u16* dst; int off;
    if (tid < XCH) { src = x; dst = xb; off = tid; }
    else {
        int r = tid - XCH;
        int seg = r / WCH; off = r % WCH;
        if (seg == 0)      { src = pw; dst = wb; }
        else if (seg == 1) { src = qw; dst = wb + D1*EMB; }
        else if (seg == 2) { src = vw; dst = wb + 2*D1*EMB; }
        else if (seg == 3) { src = ow; dst = owb; }
        else return;
    }
    float4 f = *(const float4*)(src + off * 4);
    ushort4 o;
    o.x = f2bf(f.x); o.y = f2bf(f.y); o.z = f2bf(f.z); o.w = f2bf(f.w);
    *(ushort4*)(dst + off * 4) = o;
}

// ---------------- K1: RPE MLP + decay -> A1, A2 (fp32, 112 x 576 each) ----
__global__ __launch_bounds__(576) void rpe_kernel(
    const float* __restrict__ slope,
    const float* w0a, const float* b0a, const float* wsa, const float* bsa,
    const float* woa, const float* boa,
    const float* w0b, const float* b0b, const float* wsb, const float* bsb,
    const float* wob, const float* bob,
    float* __restrict__ A1, float* __restrict__ A2)
{
    int wq  = blockIdx.x / M2;
    int row = blockIdx.x % M2;
    const float* w0 = wq ? w0b : w0a;  const float* b0 = wq ? b0b : b0a;
    const float* ws = wq ? wsb : wsa;  const float* bs = wq ? bsb : bsa;
    const float* wo = wq ? wob : woa;  const float* bo = wq ? bob : boa;
    float* A = wq ? A2 : A1;

    float tval = (row == 0 || row == 56) ? 0.0f
               : (row < 56 ? (float)row : -(float)(row - 56));
    int kexp = (row == 0 || row == 56) ? 0 : (row < 56 ? row : 112 - row);

    __shared__ float h[32], g[32];
    int t = threadIdx.x;
    if (t < 32) h[t] = tval * w0[t] + b0[t];
    __syncthreads();
    for (int L = 0; L < 3; L++) {
        if (t < 32) g[t] = fmaxf(h[t], 0.0f);
        __syncthreads();
        float hn = 0.0f;
        if (t < 32) {
            hn = bs[L * 32 + t];
            for (int k = 0; k < 32; k++)
                hn = fmaf(g[k], ws[(L * 32 + t) * 32 + k], hn);
        }
        __syncthreads();
        if (t < 32) h[t] = hn;
        __syncthreads();
    }
    if (t < 32) g[t] = fmaxf(h[t], 0.0f);
    __syncthreads();

    float o = bo[t];
    for (int k = 0; k < 32; k++)
        o = fmaf(g[k], wo[t * 32 + k], o);

    float sl = slope[t];
    sl = 0.95f + 0.05f * fminf(fmaxf(sl, 0.0f), 1.0f);
    float dec = powf(sl, (float)kexp);
    A[row * D1 + t] = o * dec;
}

// ---------------- K2: MFMA proj --------------------------------------------
// M=TOK, N=576, K=192. Tile 128x64, BK=64 (3 iters), 4 waves 2x2.
// LDS rows hold 8 16B-chunks; chunk s of row r holds global chunk s^(r&7)
// so global_load_lds stays lane-contiguous AND ds_read_b128 is conflict-free.
__global__ __launch_bounds__(256) void proj_kernel(
    const u16* __restrict__ xb, const u16* __restrict__ wb,
    const float* __restrict__ pb, const float* __restrict__ qb,
    const float* __restrict__ vb,
    u16* __restrict__ P, u16* __restrict__ QV)
{
    __shared__ u16 lds[20480];          // 40 KB: As 8192 u16, Bs 12288 u16
    u16* As = lds;
    u16* Bs = lds + 8192;
    int m0 = blockIdx.x * 128, n0 = blockIdx.y * 64;
    int t = threadIdx.x;
    int l = t & 63, wave = t >> 6;
    int wm = wave >> 1, wn = wave & 1;
    int col16 = l & 15, q = l >> 4;

    f32x4 accp[4][2], accq[4][2], accv[4][2];
    #pragma unroll
    for (int i = 0; i < 4; i++)
        #pragma unroll
        for (int j = 0; j < 2; j++) {
            accp[i][j] = (f32x4){0,0,0,0};
            accq[i][j] = (f32x4){0,0,0,0};
            accv[i][j] = (f32x4){0,0,0,0};
        }

    for (int k0 = 0; k0 < EMB; k0 += 64) {
        // stage A: 1024 chunks (128 rows x 8 chunks)
        #pragma unroll
        for (int ii = 0; ii < 4; ii++) {
            int slot = (ii * 4 + wave) * 64 + l;
            int r = slot >> 3, s = slot & 7;
            int g = s ^ (r & 7);
            async16(&As[slot * 8], xb + (m0 + r) * EMB + k0 + g * 8);
        }
        // stage B: 1536 chunks (3 mats x 64 rows x 8 chunks)
        #pragma unroll
        for (int ii = 0; ii < 6; ii++) {
            int slot = (ii * 4 + wave) * 64 + l;
            int mat = slot >> 9, cc = slot & 511;
            int r = cc >> 3, s = cc & 7;
            int g = s ^ (r & 7);
            async16(&Bs[slot * 8],
                    wb + mat * (D1 * EMB) + (n0 + r) * EMB + k0 + g * 8);
        }
        __syncthreads();

        #pragma unroll
        for (int kk = 0; kk < 2; kk++) {
            bf16x8 af[4];
            #pragma unroll
            for (int mt = 0; mt < 4; mt++) {
                int row = wm * 64 + mt * 16 + col16;
                int sw = (q + 4 * kk) ^ (col16 & 7);
                af[mt] = *(const bf16x8*)&As[row * 64 + sw * 8];
            }
            bf16x8 bfr[3][2];
            #pragma unroll
            for (int mat = 0; mat < 3; mat++)
                #pragma unroll
                for (int nt = 0; nt < 2; nt++) {
                    int row = wn * 32 + nt * 16 + col16;
                    int sw = (q + 4 * kk) ^ (col16 & 7);
                    bfr[mat][nt] = *(const bf16x8*)&Bs[mat * 4096 + row * 64 + sw * 8];
                }
            #pragma unroll
            for (int mt = 0; mt < 4; mt++)
                #pragma unroll
                for (int nt = 0; nt < 2; nt++) {
                    accp[mt][nt] = __builtin_amdgcn_mfma_f32_16x16x32_bf16(
                        af[mt], bfr[0][nt], accp[mt][nt], 0, 0, 0);
                    accq[mt][nt] = __builtin_amdgcn_mfma_f32_16x16x32_bf16(
                        af[mt], bfr[1][nt], accq[mt][nt], 0, 0, 0);
                    accv[mt][nt] = __builtin_amdgcn_mfma_f32_16x16x32_bf16(
                        af[mt], bfr[2][nt], accv[mt][nt], 0, 0, 0);
                }
        }
        __syncthreads();
    }

    // epilogue: repack each wave's 64x32 tile through LDS -> dwordx4 stores
    u16* scr = lds + wave * 2560;       // 64 rows x stride 40 u16 (80B, 16B-aligned)
    float pbv[2], qbv[2], vbv[2];
    #pragma unroll
    for (int nt = 0; nt < 2; nt++) {
        int n = n0 + wn * 32 + nt * 16 + col16;
        pbv[nt] = pb[n]; qbv[nt] = qb[n]; vbv[nt] = vb[n];
    }
    // ---- P ----
    #pragma unroll
    for (int mt = 0; mt < 4; mt++)
        #pragma unroll
        for (int nt = 0; nt < 2; nt++)
            #pragma unroll
            for (int r = 0; r < 4; r++)
                scr[(mt * 16 + q * 4 + r) * 40 + nt * 16 + col16] =
                    f2bf(silu(accp[mt][nt][r] + pbv[nt]));
    #pragma unroll
    for (int k = 0; k < 4; k++) {
        int row = k * 16 + (l >> 2), cs = (l & 3) * 8;
        uint4 v = *(const uint4*)&scr[row * 40 + cs];
        *(uint4*)&P[(m0 + wm * 64 + row) * D1 + n0 + wn * 32 + cs] = v;
    }
    // ---- QV ----
    #pragma unroll
    for (int mt = 0; mt < 4; mt++)
        #pragma unroll
        for (int nt = 0; nt < 2; nt++)
            #pragma unroll
            for (int r = 0; r < 4; r++)
                scr[(mt * 16 + q * 4 + r) * 40 + nt * 16 + col16] =
                    f2bf(silu(accq[mt][nt][r] + qbv[nt]) *
                         silu(accv[mt][nt][r] + vbv[nt]));
    #pragma unroll
    for (int k = 0; k < 4; k++) {
        int row = k * 16 + (l >> 2), cs = (l & 3) * 8;
        uint4 v = *(const uint4*)&scr[row * 40 + cs];
        *(uint4*)&QV[(m0 + wm * 64 + row) * D1 + n0 + wn * 32 + cs] = v;
    }
}

// ---------------- tno common: per-thread register-window Toeplitz ----------
// o[i] = sum_j asL[i+55-j]*q[j].  Thread (d = t&63, ig = t>>6), i0 = ig*16,
// holds asL[i0..i0+71] in 72 registers (rows >=111 zero-padded; outputs
// i>=56 discarded).  LDS d-major: qs_t stride 60, as_t stride 124.
#define TNO_BODY(QLOAD)                                                      \
    __shared__ float qs_t[64 * 60];                                          \
    __shared__ float as_t[64 * 124];                                         \
    int t = threadIdx.x;                                                     \
    for (int idx = t; idx < 64 * 14; idx += 256) {                           \
        int d = idx & 63, jg = idx >> 6;                                     \
        f32x4 v;                                                             \
        _Pragma("unroll")                                                    \
        for (int jj = 0; jj < 4; jj++) {                                     \
            int j = jg * 4 + jj;                                             \
            v[jj] = bf2f(QLOAD);                                             \
        }                                                                    \
        *(f32x4*)&qs_t[d * 60 + jg * 4] = v;                                 \
    }                                                                        \
    for (int idx = t; idx < 64 * 31; idx += 256) {                           \
        int d = idx & 63, pg = idx >> 6;                                     \
        f32x4 v;                                                             \
        _Pragma("unroll")                                                    \
        for (int jj = 0; jj < 4; jj++) {                                     \
            int p = pg * 4 + jj;                                             \
            if (p <= 110) {                                                  \
                int lg = p - 55;                                             \
                int rowi = lg + (lg < 0 ? 112 : 0);                          \
                v[jj] = Aco[rowi * D1 + d0 + d];                             \
            } else v[jj] = 0.0f;                                             \
        }                                                                    \
        *(f32x4*)&as_t[d * 124 + pg * 4] = v;                                \
    }                                                                        \
    __syncthreads();                                                         \
    int d = t & 63, ig = t >> 6;                                             \
    int i0 = ig * 16;                                                        \
    float areg[72];                                                          \
    _Pragma("unroll")                                                        \
    for (int k4 = 0; k4 < 18; k4++)                                          \
        *(f32x4*)&areg[k4 * 4] = *(const f32x4*)&as_t[d * 124 + i0 + k4 * 4];\
    float acc[16];                                                           \
    _Pragma("unroll")                                                        \
    for (int ii = 0; ii < 16; ii++) acc[ii] = 0.0f;                          \
    _Pragma("unroll")                                                        \
    for (int jg = 0; jg < 14; jg++) {                                        \
        f32x4 q4 = *(const f32x4*)&qs_t[d * 60 + jg * 4];                    \
        _Pragma("unroll")                                                    \
        for (int jj = 0; jj < 4; jj++) {                                     \
            int j = jg * 4 + jj;                                             \
            float qv = q4[jj];                                               \
            _Pragma("unroll")                                                \
            for (int ii = 0; ii < 16; ii++)                                  \
                acc[ii] = fmaf(areg[ii + 55 - j], qv, acc[ii]);              \
        }                                                                    \
    }

// ---------------- K3: Toeplitz along W -> O (bf16) ------------------------
__global__ __launch_bounds__(256) void tno_w_kernel(
    const u16* __restrict__ QV, const float* __restrict__ Aco,
    u16* __restrict__ O)
{
    int bh = blockIdx.x;            // b*56 + h
    int d0 = blockIdx.y * 64;
    TNO_BODY(QV[(bh * 56 + j) * D1 + d0 + d])
    #pragma unroll
    for (int ii = 0; ii < 16; ii++) {
        int i = i0 + ii;
        if (i < 56)
            O[(bh * 56 + i) * D1 + d0 + d] = f2bf(acc[ii]);
    }
}

// ---------------- K4: Toeplitz along H, fuse U = P .* (o1 + o2) -----------
__global__ __launch_bounds__(256) void tno_h_kernel(
    const u16* __restrict__ QV, const float* __restrict__ Aco,
    const u16* __restrict__ O, u16* __restrict__ PU)
{
    int bw = blockIdx.x;            // b*56 + w
    int b = bw / 56, wc = bw % 56;
    int d0 = blockIdx.y * 64;
    TNO_BODY(QV[((b * 56 + j) * 56 + wc) * D1 + d0 + d])
    #pragma unroll
    for (int ii = 0; ii < 16; ii++) {
        int i = i0 + ii;
        if (i < 56) {
            int idx = ((b * 56 + i) * 56 + wc) * D1 + d0 + d;
            float o = bf2f(O[idx]) + acc[ii];
            float p = bf2f(PU[idx]);
            PU[idx] = f2bf(p * o);
        }
    }
}

// ---------------- K5: MFMA outproj: out = U @ ow^T + ob -------------------
// M=TOK, N=192, K=576. Tile 128x64, BK=64 (9 iters), 4 waves 2x2.
__global__ __launch_bounds__(256) void outproj_kernel(
    const u16* __restrict__ U, const u16* __restrict__ owb,
    const float* __restrict__ ob, float* __restrict__ out)
{
    __shared__ char ldsraw[36864];     // staging 24KB; epilogue scratch 36KB
    u16* As = (u16*)ldsraw;            // 128x64 u16 = 16KB
    u16* Bs = (u16*)(ldsraw + 16384);  // 64x64 u16 = 8KB
    int m0 = blockIdx.x * 128, n0 = blockIdx.y * 64;
    int t = threadIdx.x;
    int l = t & 63, wave = t >> 6;
    int wm = wave >> 1, wn = wave & 1;
    int col16 = l & 15, q = l >> 4;

    f32x4 acc[4][2];
    #pragma unroll
    for (int i = 0; i < 4; i++)
        #pragma unroll
        for (int j = 0; j < 2; j++) acc[i][j] = (f32x4){0,0,0,0};

    for (int k0 = 0; k0 < D1; k0 += 64) {
        #pragma unroll
        for (int ii = 0; ii < 4; ii++) {
            int slot = (ii * 4 + wave) * 64 + l;
            int r = slot >> 3, s = slot & 7;
            int g = s ^ (r & 7);
            async16(&As[slot * 8], U + (m0 + r) * D1 + k0 + g * 8);
        }
        #pragma unroll
        for (int ii = 0; ii < 2; ii++) {
            int slot = (ii * 4 + wave) * 64 + l;
            int r = slot >> 3, s = slot & 7;
            int g = s ^ (r & 7);
            async16(&Bs[slot * 8], owb + (n0 + r) * D1 + k0 + g * 8);
        }
        __syncthreads();

        #pragma unroll
        for (int kk = 0; kk < 2; kk++) {
            int sw = (q + 4 * kk) ^ (col16 & 7);
            bf16x8 af[4];
            #pragma unroll
            for (int mt = 0; mt < 4; mt++)
                af[mt] = *(const bf16x8*)&As[(wm * 64 + mt * 16 + col16) * 64 + sw * 8];
            bf16x8 bfr[2];
            #pragma unroll
            for (int nt = 0; nt < 2; nt++)
                bfr[nt] = *(const bf16x8*)&Bs[(wn * 32 + nt * 16 + col16) * 64 + sw * 8];
            #pragma unroll
            for (int mt = 0; mt < 4; mt++)
                #pragma unroll
                for (int nt = 0; nt < 2; nt++)
                    acc[mt][nt] = __builtin_amdgcn_mfma_f32_16x16x32_bf16(
                        af[mt], bfr[nt], acc[mt][nt], 0, 0, 0);
        }
        __syncthreads();
    }

    // epilogue via LDS repack: per-wave 64x32 f32, stride 36 (16B aligned)
    float* scr = (float*)ldsraw + wave * 2304;
    float obv[2];
    #pragma unroll
    for (int nt = 0; nt < 2; nt++)
        obv[nt] = ob[n0 + wn * 32 + nt * 16 + col16];
    #pragma unroll
    for (int mt = 0; mt < 4; mt++)
        #pragma unroll
        for (int nt = 0; nt < 2; nt++)
            #pragma unroll
            for (int r = 0; r < 4; r++)
                scr[(mt * 16 + q * 4 + r) * 36 + nt * 16 + col16] =
                    acc[mt][nt][r] + obv[nt];
    #pragma unroll
    for (int k = 0; k < 8; k++) {
        int row = k * 8 + (l >> 3), cs = (l & 7) * 4;
        f32x4 v = *(const f32x4*)&scr[row * 36 + cs];
        *(f32x4*)&out[(m0 + wm * 64 + row) * EMB + n0 + wn * 32 + cs] = v;
    }
}

extern "C" void kernel_launch(void* const* d_in, const int* in_sizes, int n_in,
                              void* d_out, int out_size, void* d_ws, size_t ws_size,
                              hipStream_t stream)
{
    (void)in_sizes; (void)n_in; (void)out_size; (void)ws_size;
    const float* x     = (const float*)d_in[0];
    const float* p_w   = (const float*)d_in[1];
    const float* p_b   = (const float*)d_in[2];
    const float* q_w   = (const float*)d_in[3];
    const float* q_b   = (const float*)d_in[4];
    const float* v_w   = (const float*)d_in[5];
    const float* v_b   = (const float*)d_in[6];
    const float* o_w   = (const float*)d_in[7];
    const float* o_b   = (const float*)d_in[8];
    const float* slope = (const float*)d_in[9];
    const float* t1_w0 = (const float*)d_in[10];
    const float* t1_b0 = (const float*)d_in[11];
    const float* t1_ws = (const float*)d_in[12];
    const float* t1_bs = (const float*)d_in[13];
    const float* t1_wo = (const float*)d_in[14];
    const float* t1_bo = (const float*)d_in[15];
    const float* t2_w0 = (const float*)d_in[16];
    const float* t2_b0 = (const float*)d_in[17];
    const float* t2_ws = (const float*)d_in[18];
    const float* t2_bs = (const float*)d_in[19];
    const float* t2_wo = (const float*)d_in[20];
    const float* t2_bo = (const float*)d_in[21];

    char* ws = (char*)d_ws;
    float* A1 = (float*)ws;                      // 258048 B
    float* A2 = (float*)(ws + 258048);           // 258048 B
    u16*   PU = (u16*)(ws + 516096);             // 28901376 B (P, later U)
    u16*   QV = (u16*)(ws + 29417472);           // 28901376 B
    u16*   O  = (u16*)(ws + 58318848);           // 28901376 B (bf16)
    u16*   xb = (u16*)(ws + 87220224);           // 9633792 B
    u16*   wb = (u16*)(ws + 96854016);           // 663552 B
    u16*   owb= (u16*)(ws + 97517568);           // 221184 B

    convert_kernel<<<(XCH + 4*WCH + 255) / 256, 256, 0, stream>>>(
        x, p_w, q_w, v_w, o_w, xb, wb, owb);
    rpe_kernel<<<224, 576, 0, stream>>>(slope,
        t1_w0, t1_b0, t1_ws, t1_bs, t1_wo, t1_bo,
        t2_w0, t2_b0, t2_ws, t2_bs, t2_wo, t2_bo, A1, A2);
    proj_kernel<<<dim3(TOK / 128, D1 / 64), 256, 0, stream>>>(
        xb, wb, p_b, q_b, v_b, PU, QV);
    tno_w_kernel<<<dim3(NB * NN, D1 / 64), 256, 0, stream>>>(QV, A1, O);
    tno_h_kernel<<<dim3(NB * NN, D1 / 64), 256, 0, stream>>>(QV, A2, O, PU);
    outproj_kernel<<<dim3(TOK / 128, EMB / 64), 256, 0, stream>>>(
        PU, owb, o_b, (float*)d_out);
}